// Round 14
// baseline (856.255 us; speedup 1.0000x reference)
//
#include <hip/hip_runtime.h>
#include <hip/hip_bf16.h>

typedef unsigned short u16;
typedef unsigned int u32;
typedef __attribute__((ext_vector_type(8))) short short8;
typedef __attribute__((ext_vector_type(4))) float f32x4;

__device__ __forceinline__ u16 f2bf(float f) {
    union { float f; unsigned u; } v; v.f = f;
    unsigned r = v.u + 0x7fffu + ((v.u >> 16) & 1u);
    return (u16)(r >> 16);
}

__device__ __forceinline__ float fexp2(float x) {
#if __has_builtin(__builtin_amdgcn_exp2f)
    return __builtin_amdgcn_exp2f(x);
#else
    return __expf(x * 0.6931471805599453f);
#endif
}

// ---------------------------------------------------------------------------
// fp8 e4m3 pack/unpack (P pre-scaled x256; r9-r13 absmax 0.078).
// ---------------------------------------------------------------------------
#if __has_builtin(__builtin_amdgcn_cvt_pk_fp8_f32) && \
    __has_builtin(__builtin_amdgcn_cvt_f32_fp8)
#define FP8_HW 1
#else
#define FP8_HW 0
#endif

#if !FP8_HW
__device__ __forceinline__ u32 sw_fp8(float x) {  // x in [0, 448]
    union { float f; u32 u; } v; v.f = x;
    int E = (int)(v.u >> 23) - 127;
    if (x < 0.001953125f) return 0;
    if (E < -6) return (u32)(x * 512.0f + 0.5f);
    u32 m = v.u & 0x7fffffu;
    u32 r = (m + 0x80000u) >> 20;
    u32 bits = ((u32)(E + 7) << 3) + r;
    return bits > 0x7eu ? 0x7eu : bits;
}
__device__ __forceinline__ float sw_fp8d(u32 b) {
    u32 e = (b >> 3) & 15u, m = b & 7u;
    if (e == 0) return (float)m * 0.001953125f;
    union { u32 u; float f; } v; v.u = ((e + 120u) << 23) | (m << 20);
    return v.f;
}
#endif

__device__ __forceinline__ u32 fp8x4_pack(float p0, float p1, float p2, float p3) {
#if FP8_HW
    u32 v = (u32)__builtin_amdgcn_cvt_pk_fp8_f32(p0, p1, 0, false);
    v = (u32)__builtin_amdgcn_cvt_pk_fp8_f32(p2, p3, (int)v, true);
    return v;
#else
    return sw_fp8(p0) | (sw_fp8(p1) << 8) | (sw_fp8(p2) << 16) | (sw_fp8(p3) << 24);
#endif
}

#if FP8_HW
#define FP8_DEC(v, s) __builtin_amdgcn_cvt_f32_fp8((int)(v), (s))
#else
#define FP8_DEC(v, s) sw_fp8d(((v) >> ((s) * 8)) & 0xffu)
#endif

// async 16B global->LDS DMA (m97 pattern).
__device__ __forceinline__ void async_cp16(const u16* g, u16* l) {
    __builtin_amdgcn_global_load_lds(
        (const __attribute__((address_space(1))) void*)g,
        (__attribute__((address_space(3))) void*)l, 16, 0, 0);
}

// ---------------------------------------------------------------------------
// XOR-swizzled LDS GEMM cores, BK=64 (r13; zero SQ_LDS_BANK_CONFLICT).
// ---------------------------------------------------------------------------
__device__ __forceinline__ short8 mfma_ld(const u16* base, int off) {
    return *(const short8*)&base[off];
}

// 128x128x512: A [128,512] bf16 rm, B^T [128,512] bf16 rm (computes A.B^T).
__device__ __forceinline__ void gemm512(const u16* A, const u16* B,
                                        u16* As, u16* Bs,
                                        f32x4 acc[4][4], int tid) {
    const int lane = tid & 63, w = tid >> 6;
    const int quad = lane >> 4, l15 = lane & 15;
    const int wm = tid >> 7, wn = (tid >> 6) & 1;
    const int Gw = lane ^ ((lane >> 3) & 7);
    const int srow = Gw >> 3;
    const int scol = (Gw & 7) * 8;
    const int rl = l15 & 7;
    const int winl = l15 >> 3;
    int Pr[2];
#pragma unroll
    for (int h = 0; h < 2; h++)
        Pr[h] = (rl * 8 + ((quad + h * 4) ^ rl)) * 8;
    const int winA0 = (wm * 64) >> 3, winB0 = (wn * 64) >> 3;
    for (int k0 = 0; k0 < 512; k0 += 64) {
        __syncthreads();
#pragma unroll
        for (int t = 0; t < 4; t++) {
            int win = w * 4 + t;
            async_cp16(A + (size_t)(win * 8 + srow) * 512 + k0 + scol,
                       As + win * 512);
            async_cp16(B + (size_t)(win * 8 + srow) * 512 + k0 + scol,
                       Bs + win * 512);
        }
        __syncthreads();
#pragma unroll
        for (int h = 0; h < 2; h++) {
            short8 af[4], bfr[4];
#pragma unroll
            for (int i = 0; i < 4; i++)
                af[i] = mfma_ld(As, (winA0 + i * 2 + winl) * 512 + Pr[h]);
#pragma unroll
            for (int j = 0; j < 4; j++)
                bfr[j] = mfma_ld(Bs, (winB0 + j * 2 + winl) * 512 + Pr[h]);
#pragma unroll
            for (int i = 0; i < 4; i++)
#pragma unroll
                for (int j = 0; j < 4; j++)
                    acc[i][j] = __builtin_amdgcn_mfma_f32_16x16x32_bf16(
                        af[i], bfr[j], acc[i][j], 0, 0, 0);
        }
    }
}

// 64x128x512 variant (A 64 rows). As: 4096 u16, Bs: 8192 u16.
__device__ __forceinline__ void gemm512_r64(const u16* A, const u16* B,
                                            u16* As, u16* Bs,
                                            f32x4 acc[2][4], int tid) {
    const int lane = tid & 63, w = tid >> 6;
    const int quad = lane >> 4, l15 = lane & 15;
    const int wm = tid >> 7, wn = (tid >> 6) & 1;
    const int Gw = lane ^ ((lane >> 3) & 7);
    const int srow = Gw >> 3;
    const int scol = (Gw & 7) * 8;
    const int rl = l15 & 7;
    const int winl = l15 >> 3;
    int Pr[2];
#pragma unroll
    for (int h = 0; h < 2; h++)
        Pr[h] = (rl * 8 + ((quad + h * 4) ^ rl)) * 8;
    const int winA0 = (wm * 32) >> 3, winB0 = (wn * 64) >> 3;
    for (int k0 = 0; k0 < 512; k0 += 64) {
        __syncthreads();
#pragma unroll
        for (int t = 0; t < 2; t++) {
            int win = w * 2 + t;
            async_cp16(A + (size_t)(win * 8 + srow) * 512 + k0 + scol,
                       As + win * 512);
        }
#pragma unroll
        for (int t = 0; t < 4; t++) {
            int win = w * 4 + t;
            async_cp16(B + (size_t)(win * 8 + srow) * 512 + k0 + scol,
                       Bs + win * 512);
        }
        __syncthreads();
#pragma unroll
        for (int h = 0; h < 2; h++) {
            short8 af[2], bfr[4];
#pragma unroll
            for (int i = 0; i < 2; i++)
                af[i] = mfma_ld(As, (winA0 + i * 2 + winl) * 512 + Pr[h]);
#pragma unroll
            for (int j = 0; j < 4; j++)
                bfr[j] = mfma_ld(Bs, (winB0 + j * 2 + winl) * 512 + Pr[h]);
#pragma unroll
            for (int i = 0; i < 2; i++)
#pragma unroll
                for (int j = 0; j < 4; j++)
                    acc[i][j] = __builtin_amdgcn_mfma_f32_16x16x32_bf16(
                        af[i], bfr[j], acc[i][j], 0, 0, 0);
        }
    }
}

// ---------------------------------------------------------------------------
// r9-proven software grid barrier: all blocks co-resident (launch_bounds +
// capacity arithmetic). Every phase flushes state to global BEFORE the
// barrier — nothing live across it (r9/r12 spill lesson).
// ---------------------------------------------------------------------------
__device__ __forceinline__ void gridbar(u32* ctr, u32 target, int tid) {
    __syncthreads();
    __threadfence();
    if (tid == 0) {
        __hip_atomic_fetch_add(ctr, 1u, __ATOMIC_ACQ_REL,
                               __HIP_MEMORY_SCOPE_AGENT);
        int it = 0;
        while (__hip_atomic_load(ctr, __ATOMIC_ACQUIRE,
                                 __HIP_MEMORY_SCOPE_AGENT) < target &&
               it < (1 << 24)) {
            __builtin_amdgcn_s_sleep(2);
            ++it;
        }
    }
    __syncthreads();
}

// ---------------------------------------------------------------------------
// prep: [0,4096) convert X->bf16; [4096,5120) transpose weights;
// 5120: zero the 4 barrier counters (per-launch, graph-safe).
// ---------------------------------------------------------------------------
__global__ void prep(const float* __restrict__ X, const float* __restrict__ W0,
                     const float* __restrict__ W1, const float* __restrict__ W2,
                     const float* __restrict__ W3, u16* __restrict__ Xb,
                     u16* __restrict__ T0, u16* __restrict__ T1,
                     u16* __restrict__ T2, u16* __restrict__ T3,
                     u32* __restrict__ ctr) {
    __shared__ float tile[32][33];
    int id = blockIdx.x, tid = threadIdx.x;
    if (id == 5120) {
        if (tid < 4) ctr[tid] = 0;
        return;
    }
    if (id < 4096) {
        int idx = (id * 256 + tid) * 4;
        float4 v = *(const float4*)&X[idx];
        ushort4 o;
        o.x = f2bf(v.x); o.y = f2bf(v.y); o.z = f2bf(v.z); o.w = f2bf(v.w);
        *(ushort4*)&Xb[idx] = o;
        return;
    }
    int t = id - 4096;
    int z = t >> 8, rem = t & 255;
    int bo_ = (rem & 15) * 32, bi = (rem >> 4) * 32;
    const float* src; u16* dst;
    switch (z) {
        case 0: src = W0; dst = T0; break;
        case 1: src = W1; dst = T1; break;
        case 2: src = W2; dst = T2; break;
        default: src = W3; dst = T3; break;
    }
    int tx = tid & 31, ty = tid >> 5;
#pragma unroll
    for (int s = 0; s < 4; s++) {
        int i = bi + ty + s * 8;
        tile[ty + s * 8][tx] = src[i * 512 + bo_ + tx];
    }
    __syncthreads();
#pragma unroll
    for (int s = 0; s < 4; s++) {
        int o = bo_ + ty + s * 8;
        dst[o * 512 + bi + tx] = f2bf(tile[tx][ty + s * 8]);
    }
}

// ---------------------------------------------------------------------------
// MEGA: qkv |bar| pass1p |bar| reduce |bar| colsum |bar| final.
// 1024 blocks, __launch_bounds__(256,4): VGPR cap 128 (phases measured <=96),
// LDS 32 KB x4 = 128 <=160 KB -> all co-resident (r9-validated config).
// ---------------------------------------------------------------------------
__global__ __launch_bounds__(256, 4) void mega(
    const u16* Xb, const u16* Wall, const float* bq, const float* bk,
    const float* bv, u16* Qall, float2* statsP, u32* Pbuf, float* cstat,
    float* Sg, const u16* Wot, const float* bo, const float* g,
    const float* bb, const float* mean, const float* var, const float* X,
    float* out, u32* ctr) {
    __shared__ __align__(16) u16 LDS[16384];  // 32 KB, re-purposed per phase
    u16* As = LDS;
    u16* Bs = LDS + 8192;
    int tid = threadIdx.x, bid = blockIdx.x;
    int lane = tid & 63, quad = lane >> 4, l15 = lane & 15;
    int wm = tid >> 7, wn = (tid >> 6) & 1;

    // ================= phase Q: QKV projection (768 active) ================
    if (bid < 768) {
        int z = bid >> 8, rem = bid & 255;
        int m0 = (rem >> 2) * 128, n0 = (rem & 3) * 128;
        const u16* Bt = Wall + (size_t)z * 262144 + (size_t)n0 * 512;
        const float* bias = (z == 0) ? bq : (z == 1) ? bk : bv;
        const float qs = (z == 0) ? 1.44269504088896340736f : 1.0f;
        u16* C = Qall + (size_t)z * 4194304;
        f32x4 acc[4][4];
#pragma unroll
        for (int i = 0; i < 4; i++)
#pragma unroll
            for (int j = 0; j < 4; j++) acc[i][j] = (f32x4){0.f, 0.f, 0.f, 0.f};
        gemm512(Xb + (size_t)m0 * 512, Bt, As, Bs, acc, tid);
#pragma unroll
        for (int j = 0; j < 4; j++) {
            int n = n0 + wn * 64 + j * 16 + l15;
            float bvv = bias[n];
#pragma unroll
            for (int i = 0; i < 4; i++)
#pragma unroll
                for (int rg = 0; rg < 4; rg++) {
                    int m = m0 + wm * 64 + i * 16 + quad * 4 + rg;
                    C[(size_t)m * 512 + n] = f2bf((acc[i][j][rg] + bvv) * qs);
                }
        }
    }
    gridbar(ctr + 0, 1024, tid);

    // ================= phase P: score GEMM + fp8 P-store ===================
    {
        int mblk = bid & 31, nch = (bid >> 5) & 15, b = bid >> 9;
        const u16* Qp = Qall + ((size_t)(b * 4096 + mblk * 128)) * 512;
        const u16* Kbase = Qall + 4194304;
        for (int nt = 0; nt < 2; nt++) {
            const u16* K =
                Kbase + ((size_t)(b * 4096 + nch * 256 + nt * 128)) * 512;
            f32x4 acc[4][4];
#pragma unroll
            for (int i = 0; i < 4; i++)
#pragma unroll
                for (int j = 0; j < 4; j++)
                    acc[i][j] = (f32x4){0.f, 0.f, 0.f, 0.f};
            gemm512(Qp, K, As, Bs, acc, tid);
            u32* Pt =
                Pbuf + (((size_t)(b * 32 + mblk) * 16 + nch) * 2 + nt) * 4096;
            int ch = nch * 4 + nt * 2 + wn;
#pragma unroll
            for (int i = 0; i < 4; i++)
#pragma unroll
                for (int rg = 0; rg < 4; rg++) {
                    float v0 = acc[i][0][rg], v1 = acc[i][1][rg];
                    float v2 = acc[i][2][rg], v3 = acc[i][3][rg];
                    float Mt = fmaxf(fmaxf(v0, v1), fmaxf(v2, v3));
                    Mt = fmaxf(Mt, __shfl_xor(Mt, 1));
                    Mt = fmaxf(Mt, __shfl_xor(Mt, 2));
                    Mt = fmaxf(Mt, __shfl_xor(Mt, 4));
                    Mt = fmaxf(Mt, __shfl_xor(Mt, 8));
                    float e8 = Mt - 8.0f;  // x256 pre-scale for fp8 range
                    float p0 = fexp2(v0 - e8), p1 = fexp2(v1 - e8);
                    float p2 = fexp2(v2 - e8), p3 = fexp2(v3 - e8);
                    Pt[(i * 4 + rg) * 256 + tid] = fp8x4_pack(p0, p1, p2, p3);
                    float L = p0 + p1 + p2 + p3;
                    L += __shfl_xor(L, 1);
                    L += __shfl_xor(L, 2);
                    L += __shfl_xor(L, 4);
                    L += __shfl_xor(L, 8);
                    if (l15 == 0)
                        statsP[((size_t)(b * 64 + ch)) * 4096 + mblk * 128 +
                               wm * 64 + i * 16 + quad * 4 + rg] =
                            make_float2(Mt, L * 0.00390625f);
                }
        }
    }
    gridbar(ctr + 1, 1024, tid);

    // ===== phase R: c = M + log2(Z) per row; zero Sg (8 rows/block) ========
    {
        int row = bid * 8 + (tid >> 5);  // 0..8191
        int q = tid & 31;                // 2 chunks per thread
        int b = row >> 12, m = row & 4095;
        const float2* sp = statsP + (size_t)b * 64 * 4096 + m;
        float2 pa = sp[(size_t)(q * 2) * 4096];
        float2 pb = sp[(size_t)(q * 2 + 1) * 4096];
        float M = fmaxf(pa.x, pb.x);
        float Z = pa.y * fexp2(pa.x - M) + pb.y * fexp2(pb.x - M);
#pragma unroll
        for (int d = 1; d < 32; d <<= 1) {
            float Mo = __shfl_xor(M, d);
            float Zo = __shfl_xor(Z, d);
            float Mn = fmaxf(M, Mo);
            Z = Z * fexp2(M - Mn) + Zo * fexp2(Mo - Mn);
            M = Mn;
        }
        if (q == 0) {
            cstat[row] = M + __log2f(Z);
            Sg[row] = 0.f;
        }
    }
    gridbar(ctr + 2, 1024, tid);

    // ================= phase S: weighted column sums =======================
    {
        int nch = bid & 15, y = (bid >> 4) & 31, b = bid >> 9;
        int nt = y & 1, mgrp = y >> 1;
        int ch = nch * 4 + nt * 2 + wn;
        const float2* Sp = statsP + ((size_t)(b * 64 + ch)) * 4096;
        const float* Cp = cstat + (size_t)b * 4096;
        float cp[4] = {0.f, 0.f, 0.f, 0.f};
        for (int mb = 0; mb < 2; mb++) {
            int mblk = mgrp * 2 + mb;
            const u32* Pt =
                Pbuf + (((size_t)(b * 32 + mblk) * 16 + nch) * 2 + nt) * 4096;
#pragma unroll
            for (int i = 0; i < 4; i++) {
                int r0 = mblk * 128 + wm * 64 + i * 16 + quad * 4;
                float4 s01 = *(const float4*)&Sp[r0];
                float4 s23 = *(const float4*)&Sp[r0 + 2];
                float4 cv = *(const float4*)&Cp[r0];
                float fv[4] = {fexp2(s01.x - 8.0f - cv.x),
                               fexp2(s01.z - 8.0f - cv.y),
                               fexp2(s23.x - 8.0f - cv.z),
                               fexp2(s23.z - 8.0f - cv.w)};
                float fm = fmaxf(fmaxf(fv[0], fv[1]), fmaxf(fv[2], fv[3]));
                if (fm > 3.469446951953614e-18f) {  // 2^-58 F-skip (r11)
#pragma unroll
                    for (int rg = 0; rg < 4; rg++) {
                        u32 e = Pt[(i * 4 + rg) * 256 + tid];
                        cp[0] += FP8_DEC(e, 0) * fv[rg];
                        cp[1] += FP8_DEC(e, 1) * fv[rg];
                        cp[2] += FP8_DEC(e, 2) * fv[rg];
                        cp[3] += FP8_DEC(e, 3) * fv[rg];
                    }
                }
            }
        }
#pragma unroll
        for (int j = 0; j < 4; j++) {
            float s = cp[j];
            s += __shfl_xor(s, 16);
            s += __shfl_xor(s, 32);
            if (lane < 16)
                atomicAdd(&Sg[b * 4096 + nch * 256 + nt * 128 + wn * 64 +
                              j * 16 + lane],
                          s);
        }
    }
    gridbar(ctr + 3, 1024, tid);

    // ================= phase F: output GEMM + epilogue (512 active) ========
    if (bid < 512) {
        int m0 = (bid & 127) * 64, n0 = (bid >> 7) * 128;
        const u16* Vb = Qall + 2 * 4194304;
        f32x4 acc[2][4];
#pragma unroll
        for (int i = 0; i < 2; i++)
#pragma unroll
            for (int j = 0; j < 4; j++) acc[i][j] = (f32x4){0.f, 0.f, 0.f, 0.f};
        gemm512_r64(Vb + (size_t)m0 * 512, Wot + (size_t)n0 * 512, LDS,
                    LDS + 4096, acc, tid);
        float sc[2][4];
#pragma unroll
        for (int i = 0; i < 2; i++) {
            float4 s = *(const float4*)&Sg[m0 + wm * 32 + i * 16 + quad * 4];
            float v[4] = {s.x, s.y, s.z, s.w};
#pragma unroll
            for (int rg = 0; rg < 4; rg++) sc[i][rg] = v[rg] / (1e-9f + v[rg]);
        }
#pragma unroll
        for (int j = 0; j < 4; j++) {
            int n = n0 + wn * 64 + j * 16 + l15;
            float aj = rsqrtf(var[n] + 1e-5f) * g[n];
            float cj = bb[n] - mean[n] * aj;
            float bj = bo[n];
#pragma unroll
            for (int i = 0; i < 2; i++)
#pragma unroll
                for (int rg = 0; rg < 4; rg++) {
                    int m = m0 + wm * 32 + i * 16 + quad * 4 + rg;
                    float x = acc[i][j][rg] * sc[i][rg] + bj;
                    float y = x * aj + cj;
                    out[(size_t)m * 512 + n] =
                        fmaxf(y, 0.f) + X[(size_t)m * 512 + n];
                }
        }
    }
}

// ---------------------------------------------------------------------------
extern "C" void kernel_launch(void* const* d_in, const int* in_sizes, int n_in,
                              void* d_out, int out_size, void* d_ws, size_t ws_size,
                              hipStream_t stream) {
    const float* X  = (const float*)d_in[0];
    const float* Wq = (const float*)d_in[1];
    const float* Wk = (const float*)d_in[2];
    const float* Wv = (const float*)d_in[3];
    const float* Wo = (const float*)d_in[4];
    const float* bq = (const float*)d_in[5];
    const float* bk = (const float*)d_in[6];
    const float* bv = (const float*)d_in[7];
    const float* bo = (const float*)d_in[8];
    const float* g    = (const float*)d_in[9];
    const float* bb   = (const float*)d_in[10];
    const float* mean = (const float*)d_in[11];
    const float* var  = (const float*)d_in[12];
    float* out = (float*)d_out;

    char* ws = (char*)d_ws;
    u16* Xb  = (u16*)(ws + 0);                    // 8 MB
    u16* Wqt = (u16*)(ws + 8388608);              // 4x512KB (Wq,Wk,Wv,Wo)
    u16* Wot = (u16*)(ws + 9961472);
    u16* Qb  = (u16*)(ws + 10485760);             // Q,K,V contiguous 3x8MB
    float2* statsP = (float2*)(ws + 35651584);    // [b][64][4096] f2 = 4 MB
    float* Sg      = (float*)(ws + 39845888);     // 32 KB
    float* cstat   = (float*)(ws + 39878656);     // 32 KB
    u32* ctr       = (u32*)(ws + 39911424);       // 4 counters
    u32* Pbuf      = (u32*)(ws + 39911680);       // 32 MB fp8 P

    prep<<<5121, 256, 0, stream>>>(X, Wq, Wk, Wv, Wo, Xb, Wqt, Wqt + 262144,
                                   Wqt + 524288, Wot, ctr);
    mega<<<1024, 256, 0, stream>>>(Xb, Wqt, bq, bk, bv, Qb, statsP, Pbuf,
                                   cstat, Sg, Wot, bo, g, bb, mean, var, X,
                                   out, ctr);
}

// Round 15
// 205.473 us; speedup vs baseline: 4.1672x; 4.1672x over previous
//
#include <hip/hip_runtime.h>
#include <hip/hip_bf16.h>

typedef unsigned short u16;
typedef unsigned int u32;
typedef __attribute__((ext_vector_type(8))) short short8;
typedef __attribute__((ext_vector_type(4))) float f32x4;

__device__ __forceinline__ u16 f2bf(float f) {
    union { float f; unsigned u; } v; v.f = f;
    unsigned r = v.u + 0x7fffu + ((v.u >> 16) & 1u);
    return (u16)(r >> 16);
}

__device__ __forceinline__ float fexp2(float x) {
#if __has_builtin(__builtin_amdgcn_exp2f)
    return __builtin_amdgcn_exp2f(x);
#else
    return __expf(x * 0.6931471805599453f);
#endif
}

// ---------------------------------------------------------------------------
// DPP 16-lane butterfly (r15): __shfl_xor lowers to ds_swizzle (~5.8 cyc DS);
// DPP row ops fuse into the max/add as ONE full-rate VALU op. Masks
// {1,2,7,15} (quad_perm[1,0,3,2]=0xB1, quad_perm[2,3,0,1]=0x4E,
// row_half_mirror=0x141, row_mirror=0x140) are GF(2)-independent -> valid
// butterfly over each contiguous 16-lane row (= our quad*16+l15 groups).
// ---------------------------------------------------------------------------
template <int CTRL>
__device__ __forceinline__ float fdpp(float x) {
    int xi = __builtin_bit_cast(int, x);
    int r = __builtin_amdgcn_update_dpp(0, xi, CTRL, 0xF, 0xF, true);
    return __builtin_bit_cast(float, r);
}
__device__ __forceinline__ float dpp_max16(float m) {
    m = fmaxf(m, fdpp<0xB1>(m));   // xor 1
    m = fmaxf(m, fdpp<0x4E>(m));   // xor 2
    m = fmaxf(m, fdpp<0x141>(m));  // xor 7 (row_half_mirror)
    m = fmaxf(m, fdpp<0x140>(m));  // xor 15 (row_mirror)
    return m;
}
__device__ __forceinline__ float dpp_sum16(float s) {
    s += fdpp<0xB1>(s);
    s += fdpp<0x4E>(s);
    s += fdpp<0x141>(s);
    s += fdpp<0x140>(s);
    return s;
}

// ---------------------------------------------------------------------------
// fp8 e4m3 pack/unpack (P pre-scaled x256; r9-r13 absmax 0.078).
// ---------------------------------------------------------------------------
#if __has_builtin(__builtin_amdgcn_cvt_pk_fp8_f32) && \
    __has_builtin(__builtin_amdgcn_cvt_f32_fp8)
#define FP8_HW 1
#else
#define FP8_HW 0
#endif

#if !FP8_HW
__device__ __forceinline__ u32 sw_fp8(float x) {  // x in [0, 448]
    union { float f; u32 u; } v; v.f = x;
    int E = (int)(v.u >> 23) - 127;
    if (x < 0.001953125f) return 0;
    if (E < -6) return (u32)(x * 512.0f + 0.5f);
    u32 m = v.u & 0x7fffffu;
    u32 r = (m + 0x80000u) >> 20;
    u32 bits = ((u32)(E + 7) << 3) + r;
    return bits > 0x7eu ? 0x7eu : bits;
}
__device__ __forceinline__ float sw_fp8d(u32 b) {
    u32 e = (b >> 3) & 15u, m = b & 7u;
    if (e == 0) return (float)m * 0.001953125f;
    union { u32 u; float f; } v; v.u = ((e + 120u) << 23) | (m << 20);
    return v.f;
}
#endif

__device__ __forceinline__ u32 fp8x4_pack(float p0, float p1, float p2, float p3) {
#if FP8_HW
    u32 v = (u32)__builtin_amdgcn_cvt_pk_fp8_f32(p0, p1, 0, false);
    v = (u32)__builtin_amdgcn_cvt_pk_fp8_f32(p2, p3, (int)v, true);
    return v;
#else
    return sw_fp8(p0) | (sw_fp8(p1) << 8) | (sw_fp8(p2) << 16) | (sw_fp8(p3) << 24);
#endif
}

#if FP8_HW
#define FP8_DEC(v, s) __builtin_amdgcn_cvt_f32_fp8((int)(v), (s))
#else
#define FP8_DEC(v, s) sw_fp8d(((v) >> ((s) * 8)) & 0xffu)
#endif

// async 16B global->LDS DMA (m97 pattern).
__device__ __forceinline__ void async_cp16(const u16* g, u16* l) {
    __builtin_amdgcn_global_load_lds(
        (const __attribute__((address_space(1))) void*)g,
        (__attribute__((address_space(3))) void*)l, 16, 0, 0);
}

// ---------------------------------------------------------------------------
// XOR-swizzled LDS GEMM cores, BK=64 (r13; zero SQ_LDS_BANK_CONFLICT).
// ---------------------------------------------------------------------------
__device__ __forceinline__ short8 mfma_ld(const u16* base, int off) {
    return *(const short8*)&base[off];
}

// 128x128x512: A [128,512] bf16 rm, B^T [128,512] bf16 rm (computes A.B^T).
__device__ __forceinline__ void gemm512(const u16* __restrict__ A,
                                        const u16* __restrict__ B,
                                        u16* As, u16* Bs,
                                        f32x4 acc[4][4], int tid) {
    const int lane = tid & 63, w = tid >> 6;
    const int quad = lane >> 4, l15 = lane & 15;
    const int wm = tid >> 7, wn = (tid >> 6) & 1;
    const int Gw = lane ^ ((lane >> 3) & 7);
    const int srow = Gw >> 3;
    const int scol = (Gw & 7) * 8;
    const int rl = l15 & 7;
    const int winl = l15 >> 3;
    int Pr[2];
#pragma unroll
    for (int h = 0; h < 2; h++)
        Pr[h] = (rl * 8 + ((quad + h * 4) ^ rl)) * 8;
    const int winA0 = (wm * 64) >> 3, winB0 = (wn * 64) >> 3;
    for (int k0 = 0; k0 < 512; k0 += 64) {
        __syncthreads();
#pragma unroll
        for (int t = 0; t < 4; t++) {
            int win = w * 4 + t;
            async_cp16(A + (size_t)(win * 8 + srow) * 512 + k0 + scol,
                       As + win * 512);
            async_cp16(B + (size_t)(win * 8 + srow) * 512 + k0 + scol,
                       Bs + win * 512);
        }
        __syncthreads();
#pragma unroll
        for (int h = 0; h < 2; h++) {
            short8 af[4], bfr[4];
#pragma unroll
            for (int i = 0; i < 4; i++)
                af[i] = mfma_ld(As, (winA0 + i * 2 + winl) * 512 + Pr[h]);
#pragma unroll
            for (int j = 0; j < 4; j++)
                bfr[j] = mfma_ld(Bs, (winB0 + j * 2 + winl) * 512 + Pr[h]);
#pragma unroll
            for (int i = 0; i < 4; i++)
#pragma unroll
                for (int j = 0; j < 4; j++)
                    acc[i][j] = __builtin_amdgcn_mfma_f32_16x16x32_bf16(
                        af[i], bfr[j], acc[i][j], 0, 0, 0);
        }
    }
}

// 64x128x512 variant (A 64 rows). As: 4096 u16, Bs: 8192 u16.
__device__ __forceinline__ void gemm512_r64(const u16* __restrict__ A,
                                            const u16* __restrict__ B,
                                            u16* As, u16* Bs,
                                            f32x4 acc[2][4], int tid) {
    const int lane = tid & 63, w = tid >> 6;
    const int quad = lane >> 4, l15 = lane & 15;
    const int wm = tid >> 7, wn = (tid >> 6) & 1;
    const int Gw = lane ^ ((lane >> 3) & 7);
    const int srow = Gw >> 3;
    const int scol = (Gw & 7) * 8;
    const int rl = l15 & 7;
    const int winl = l15 >> 3;
    int Pr[2];
#pragma unroll
    for (int h = 0; h < 2; h++)
        Pr[h] = (rl * 8 + ((quad + h * 4) ^ rl)) * 8;
    const int winA0 = (wm * 32) >> 3, winB0 = (wn * 64) >> 3;
    for (int k0 = 0; k0 < 512; k0 += 64) {
        __syncthreads();
#pragma unroll
        for (int t = 0; t < 2; t++) {
            int win = w * 2 + t;
            async_cp16(A + (size_t)(win * 8 + srow) * 512 + k0 + scol,
                       As + win * 512);
        }
#pragma unroll
        for (int t = 0; t < 4; t++) {
            int win = w * 4 + t;
            async_cp16(B + (size_t)(win * 8 + srow) * 512 + k0 + scol,
                       Bs + win * 512);
        }
        __syncthreads();
#pragma unroll
        for (int h = 0; h < 2; h++) {
            short8 af[2], bfr[4];
#pragma unroll
            for (int i = 0; i < 2; i++)
                af[i] = mfma_ld(As, (winA0 + i * 2 + winl) * 512 + Pr[h]);
#pragma unroll
            for (int j = 0; j < 4; j++)
                bfr[j] = mfma_ld(Bs, (winB0 + j * 2 + winl) * 512 + Pr[h]);
#pragma unroll
            for (int i = 0; i < 2; i++)
#pragma unroll
                for (int j = 0; j < 4; j++)
                    acc[i][j] = __builtin_amdgcn_mfma_f32_16x16x32_bf16(
                        af[i], bfr[j], acc[i][j], 0, 0, 0);
        }
    }
}

// ---------------------------------------------------------------------------
// Fused prep: [0,4096) convert X->bf16; [4096,5120) transpose weights;
// 5120: zero Sg (per-launch, graph-safe).
// ---------------------------------------------------------------------------
__global__ void prep(const float* __restrict__ X, const float* __restrict__ W0,
                     const float* __restrict__ W1, const float* __restrict__ W2,
                     const float* __restrict__ W3, u16* __restrict__ Xb,
                     u16* __restrict__ T0, u16* __restrict__ T1,
                     u16* __restrict__ T2, u16* __restrict__ T3,
                     float* __restrict__ Sg) {
    __shared__ float tile[32][33];
    int id = blockIdx.x, tid = threadIdx.x;
    if (id == 5120) {
        float4 z = {0.f, 0.f, 0.f, 0.f};
#pragma unroll
        for (int t = 0; t < 8; t++) ((float4*)Sg)[tid + t * 256] = z;
        return;
    }
    if (id < 4096) {
        int idx = (id * 256 + tid) * 4;
        float4 v = *(const float4*)&X[idx];
        ushort4 o;
        o.x = f2bf(v.x); o.y = f2bf(v.y); o.z = f2bf(v.z); o.w = f2bf(v.w);
        *(ushort4*)&Xb[idx] = o;
        return;
    }
    int t = id - 4096;
    int z = t >> 8, rem = t & 255;
    int bo_ = (rem & 15) * 32, bi = (rem >> 4) * 32;
    const float* src; u16* dst;
    switch (z) {
        case 0: src = W0; dst = T0; break;
        case 1: src = W1; dst = T1; break;
        case 2: src = W2; dst = T2; break;
        default: src = W3; dst = T3; break;
    }
    int tx = tid & 31, ty = tid >> 5;
#pragma unroll
    for (int s = 0; s < 4; s++) {
        int i = bi + ty + s * 8;
        tile[ty + s * 8][tx] = src[i * 512 + bo_ + tx];
    }
    __syncthreads();
#pragma unroll
    for (int s = 0; s < 4; s++) {
        int o = bo_ + ty + s * 8;
        dst[o * 512 + bi + tx] = f2bf(tile[tx][ty + s * 8]);
    }
}

// ---------------------------------------------------------------------------
// Fused QKV projection. z==0 (Q) scaled by log2(e) -> base-2 score domain.
// ---------------------------------------------------------------------------
__global__ __launch_bounds__(256) void gemm_qkv(
    const u16* __restrict__ Xb, const u16* __restrict__ Wall,
    const float* __restrict__ bq, const float* __restrict__ bk,
    const float* __restrict__ bv, u16* __restrict__ Qall) {
    __shared__ __align__(16) u16 As[8192];
    __shared__ __align__(16) u16 Bs[8192];
    int tid = threadIdx.x;
    int m0 = blockIdx.x * 128, n0 = blockIdx.y * 128, z = blockIdx.z;
    const u16* Bt = Wall + (size_t)z * 262144 + (size_t)n0 * 512;
    const float* bias = (z == 0) ? bq : (z == 1) ? bk : bv;
    const float qs = (z == 0) ? 1.44269504088896340736f : 1.0f;
    u16* C = Qall + (size_t)z * 4194304;
    f32x4 acc[4][4];
#pragma unroll
    for (int i = 0; i < 4; i++)
#pragma unroll
        for (int j = 0; j < 4; j++) acc[i][j] = (f32x4){0.f, 0.f, 0.f, 0.f};
    gemm512(Xb + (size_t)m0 * 512, Bt, As, Bs, acc, tid);
    int lane = tid & 63, quad = lane >> 4, l15 = lane & 15;
    int wm = tid >> 7, wn = (tid >> 6) & 1;
#pragma unroll
    for (int j = 0; j < 4; j++) {
        int n = n0 + wn * 64 + j * 16 + l15;
        float bvv = bias[n];
#pragma unroll
        for (int i = 0; i < 4; i++)
#pragma unroll
            for (int rg = 0; rg < 4; rg++) {
                int m = m0 + wm * 64 + i * 16 + quad * 4 + rg;
                C[(size_t)m * 512 + n] = f2bf((acc[i][j][rg] + bvv) * qs);
            }
    }
}

// ---------------------------------------------------------------------------
// Pass 1, fp8 P-store (r13 structure + r15 DPP reductions): per 128x128
// score tile, per-64-col-chunk row-max Mt via DPP butterfly (VALU, not DS);
// P = exp2(s - Mt + 8) fp8x4, value-major [g][tid]; stats (Mt, L).
// grid (32, 16, 2).
// ---------------------------------------------------------------------------
__global__ __launch_bounds__(256) void attn_pass1p(
    const u16* __restrict__ Qb, const u16* __restrict__ Kb,
    float2* __restrict__ statsP, u32* __restrict__ Pbuf) {
    __shared__ __align__(16) u16 As[8192];
    __shared__ __align__(16) u16 Bs[8192];
    int tid = threadIdx.x;
    int mblk = blockIdx.x, nch = blockIdx.y, b = blockIdx.z;
    const u16* Q = Qb + ((size_t)(b * 4096 + mblk * 128)) * 512;
    int lane = tid & 63, quad = lane >> 4, l15 = lane & 15;
    int wm = tid >> 7, wn = (tid >> 6) & 1;
    for (int nt = 0; nt < 2; nt++) {
        const u16* K = Kb + ((size_t)(b * 4096 + nch * 256 + nt * 128)) * 512;
        f32x4 acc[4][4];
#pragma unroll
        for (int i = 0; i < 4; i++)
#pragma unroll
            for (int j = 0; j < 4; j++) acc[i][j] = (f32x4){0.f, 0.f, 0.f, 0.f};
        gemm512(Q, K, As, Bs, acc, tid);
        u32* Pt = Pbuf + (((size_t)(b * 32 + mblk) * 16 + nch) * 2 + nt) * 4096;
        int ch = nch * 4 + nt * 2 + wn;
#pragma unroll
        for (int i = 0; i < 4; i++)
#pragma unroll
            for (int rg = 0; rg < 4; rg++) {
                float v0 = acc[i][0][rg], v1 = acc[i][1][rg];
                float v2 = acc[i][2][rg], v3 = acc[i][3][rg];
                float Mt = fmaxf(fmaxf(v0, v1), fmaxf(v2, v3));
                Mt = dpp_max16(Mt);  // uniform over the 16 l15 lanes
                float e8 = Mt - 8.0f;  // x256 pre-scale for fp8 range
                float p0 = fexp2(v0 - e8), p1 = fexp2(v1 - e8);
                float p2 = fexp2(v2 - e8), p3 = fexp2(v3 - e8);
                Pt[(i * 4 + rg) * 256 + tid] = fp8x4_pack(p0, p1, p2, p3);
                float L = dpp_sum16(p0 + p1 + p2 + p3);
                if (l15 == 0)
                    statsP[((size_t)(b * 64 + ch)) * 4096 + mblk * 128 +
                           wm * 64 + i * 16 + quad * 4 + rg] =
                        make_float2(Mt, L * 0.00390625f);  // true L_ch
            }
    }
}

// ---------------------------------------------------------------------------
// c = M + log2(Z) per row. Separate kernel (r10: fusing into colsum = 64x
// redundancy, +10us; r7: retained-array version spilled). grid 32 x 256.
// ---------------------------------------------------------------------------
__global__ void reduce_stats2(const float2* __restrict__ statsP,
                              float* __restrict__ cstat) {
    int t = blockIdx.x * 256 + threadIdx.x;
    int b = t >> 12, m = t & 4095;
    const float2* sp = statsP + (size_t)b * 64 * 4096 + m;
    float M = -INFINITY;
#pragma unroll 4
    for (int ch = 0; ch < 64; ch++) M = fmaxf(M, sp[(size_t)ch * 4096].x);
    float Z = 0.f;
#pragma unroll 4
    for (int ch = 0; ch < 64; ch++) {
        float2 p = sp[(size_t)ch * 4096];
        Z += p.y * fexp2(p.x - M);
    }
    cstat[t] = M + __log2f(Z);
}

// ---------------------------------------------------------------------------
// Weighted column sums: S[n] += sum_m P_fp8[m,n] * exp2(Mt[m]-8-c[m]).
// F-SKIP (2^-58): dropped mass/col <= 4096*256*2^-58 = 2^-38, scale err
// <=3.6e-3. grid (nch=16, y = nt + 2*mgrp (16 mgrps of 2 mblks), b=2).
// ---------------------------------------------------------------------------
__global__ __launch_bounds__(256) void colsum(
    const u32* __restrict__ Pbuf, const float2* __restrict__ statsP,
    const float* __restrict__ cstat, float* __restrict__ Sg) {
    int tid = threadIdx.x, lane = tid & 63;
    int wm = tid >> 7, wn = (tid >> 6) & 1, quad = lane >> 4;
    int nch = blockIdx.x, nt = blockIdx.y & 1, mgrp = blockIdx.y >> 1;
    int b = blockIdx.z;
    int ch = nch * 4 + nt * 2 + wn;
    const float2* Sp = statsP + ((size_t)(b * 64 + ch)) * 4096;
    const float* Cp = cstat + (size_t)b * 4096;
    float cp[4] = {0.f, 0.f, 0.f, 0.f};
    for (int mb = 0; mb < 2; mb++) {
        int mblk = mgrp * 2 + mb;
        const u32* Pt =
            Pbuf + (((size_t)(b * 32 + mblk) * 16 + nch) * 2 + nt) * 4096;
#pragma unroll
        for (int i = 0; i < 4; i++) {
            int r0 = mblk * 128 + wm * 64 + i * 16 + quad * 4;
            float4 s01 = *(const float4*)&Sp[r0];      // (M0,L0,M1,L1)
            float4 s23 = *(const float4*)&Sp[r0 + 2];  // (M2,L2,M3,L3)
            float4 cv = *(const float4*)&Cp[r0];
            float fv[4] = {fexp2(s01.x - 8.0f - cv.x),
                           fexp2(s01.z - 8.0f - cv.y),
                           fexp2(s23.x - 8.0f - cv.z),
                           fexp2(s23.z - 8.0f - cv.w)};
            float fm = fmaxf(fmaxf(fv[0], fv[1]), fmaxf(fv[2], fv[3]));
            if (fm > 3.469446951953614e-18f) {  // 2^-58: see header comment
#pragma unroll
                for (int rg = 0; rg < 4; rg++) {
                    u32 e = Pt[(i * 4 + rg) * 256 + tid];
                    cp[0] += FP8_DEC(e, 0) * fv[rg];
                    cp[1] += FP8_DEC(e, 1) * fv[rg];
                    cp[2] += FP8_DEC(e, 2) * fv[rg];
                    cp[3] += FP8_DEC(e, 3) * fv[rg];
                }
            }
        }
    }
#pragma unroll
    for (int j = 0; j < 4; j++) {
        float s = cp[j];
        s += __shfl_xor(s, 16);
        s += __shfl_xor(s, 32);
        if (lane < 16)
            atomicAdd(&Sg[b * 4096 + nch * 256 + nt * 128 + wn * 64 + j * 16 + lane], s);
    }
}

// ---------------------------------------------------------------------------
// Final: out = relu(BN((V*rowscale) . Wo^T + bo)) + X  (fp32 out)
// 64x128 tiles, grid (128, 4). m0 in [0,8192) == flat (b,m).
// ---------------------------------------------------------------------------
__global__ __launch_bounds__(256) void gemm_final(
    const u16* __restrict__ A, const u16* __restrict__ Bt,
    const float* __restrict__ Sg, const float* __restrict__ bo,
    const float* __restrict__ g, const float* __restrict__ bb,
    const float* __restrict__ mean, const float* __restrict__ var,
    const float* __restrict__ X, float* __restrict__ out) {
    __shared__ __align__(16) u16 As[4096];
    __shared__ __align__(16) u16 Bs[8192];
    int tid = threadIdx.x;
    int m0 = blockIdx.x * 64, n0 = blockIdx.y * 128;
    f32x4 acc[2][4];
#pragma unroll
    for (int i = 0; i < 2; i++)
#pragma unroll
        for (int j = 0; j < 4; j++) acc[i][j] = (f32x4){0.f, 0.f, 0.f, 0.f};
    gemm512_r64(A + (size_t)m0 * 512, Bt + (size_t)n0 * 512, As, Bs, acc, tid);
    int lane = tid & 63, quad = lane >> 4, l15 = lane & 15;
    int wm = tid >> 7, wn = (tid >> 6) & 1;
    float sc[2][4];
#pragma unroll
    for (int i = 0; i < 2; i++) {
        float4 s = *(const float4*)&Sg[m0 + wm * 32 + i * 16 + quad * 4];
        float v[4] = {s.x, s.y, s.z, s.w};
#pragma unroll
        for (int rg = 0; rg < 4; rg++) sc[i][rg] = v[rg] / (1e-9f + v[rg]);
    }
#pragma unroll
    for (int j = 0; j < 4; j++) {
        int n = n0 + wn * 64 + j * 16 + l15;
        float aj = rsqrtf(var[n] + 1e-5f) * g[n];
        float cj = bb[n] - mean[n] * aj;
        float bj = bo[n];
#pragma unroll
        for (int i = 0; i < 2; i++)
#pragma unroll
            for (int rg = 0; rg < 4; rg++) {
                int m = m0 + wm * 32 + i * 16 + quad * 4 + rg;
                float x = acc[i][j][rg] * sc[i][rg] + bj;
                float y = x * aj + cj;
                out[(size_t)m * 512 + n] = fmaxf(y, 0.f) + X[(size_t)m * 512 + n];
            }
    }
}

// ---------------------------------------------------------------------------
extern "C" void kernel_launch(void* const* d_in, const int* in_sizes, int n_in,
                              void* d_out, int out_size, void* d_ws, size_t ws_size,
                              hipStream_t stream) {
    const float* X  = (const float*)d_in[0];
    const float* Wq = (const float*)d_in[1];
    const float* Wk = (const float*)d_in[2];
    const float* Wv = (const float*)d_in[3];
    const float* Wo = (const float*)d_in[4];
    const float* bq = (const float*)d_in[5];
    const float* bk = (const float*)d_in[6];
    const float* bv = (const float*)d_in[7];
    const float* bo = (const float*)d_in[8];
    const float* g    = (const float*)d_in[9];
    const float* bb   = (const float*)d_in[10];
    const float* mean = (const float*)d_in[11];
    const float* var  = (const float*)d_in[12];
    float* out = (float*)d_out;

    char* ws = (char*)d_ws;
    u16* Xb  = (u16*)(ws + 0);                    // 8 MB
    u16* Wqt = (u16*)(ws + 8388608);              // 4x512KB (Wq,Wk,Wv,Wo)
    u16* Wot = (u16*)(ws + 9961472);
    u16* Qb  = (u16*)(ws + 10485760);             // Q,K,V contiguous 3x8MB
    u16* Kb  = (u16*)(ws + 18874368);
    u16* Vb  = (u16*)(ws + 27262976);
    float2* statsP = (float2*)(ws + 35651584);    // [b][64][4096] f2 = 4 MB
    float* Sg      = (float*)(ws + 39845888);     // 32 KB
    float* cstat   = (float*)(ws + 39878656);     // 32 KB
    u32* Pbuf      = (u32*)(ws + 39911424);       // 32 MB fp8 P

    prep<<<5121, 256, 0, stream>>>(X, Wq, Wk, Wv, Wo, Xb, Wqt, Wqt + 262144,
                                   Wqt + 524288, Wot, Sg);
    gemm_qkv<<<dim3(64, 4, 3), 256, 0, stream>>>(Xb, Wqt, bq, bk, bv, Qb);
    attn_pass1p<<<dim3(32, 16, 2), 256, 0, stream>>>(Qb, Kb, statsP, Pbuf);
    reduce_stats2<<<32, 256, 0, stream>>>(statsP, cstat);
    colsum<<<dim3(16, 32, 2), 256, 0, stream>>>(Pbuf, statsP, cstat, Sg);
    gemm_final<<<dim3(128, 4), 256, 0, stream>>>(Vb, Wot, Sg, bo, g, bb, mean, var,
                                                 X, out);
}